// Round 1
// baseline (182.892 us; speedup 1.0000x reference)
//
#include <hip/hip_runtime.h>
#include <hip/hip_bf16.h>
#include <stdint.h>

typedef __attribute__((ext_vector_type(8))) short bf16x8;
typedef __attribute__((ext_vector_type(4))) float f32x4;

#define N_IMG 32
#define CIN 128
#define COUT 256
#define HH 56
#define HW (HH*HH)            // 3136
#define HP 58
#define XP_NSTRIDE (HP*HP*CIN)  // 430592 elems per image
#define PXTOT (N_IMG*HW)        // 100352

// ws layout (bytes)
#define XP_BYTES   27557888u    // 32*430592*2
#define WT_BYTES   589824u      // 9*256*128*2
#define INV_BYTES  12544u
#define STATS_BYTES 2048u

__device__ __forceinline__ unsigned short f2bf(float f) {
  unsigned int u = __builtin_bit_cast(unsigned int, f);
  unsigned int r = u + 0x7FFFu + ((u >> 16) & 1u);
  return (unsigned short)(r >> 16);
}

__device__ __forceinline__ void gload_lds16(const void* g, void* l) {
  __builtin_amdgcn_global_load_lds((const __attribute__((address_space(1))) void*)g,
                                   (__attribute__((address_space(3))) void*)l, 16, 0, 0);
}

__global__ void invperm_kernel(const int* __restrict__ perm, int* __restrict__ inv) {
  int i = blockIdx.x * 256 + threadIdx.x;
  if (i < HW) inv[perm[i]] = i;
}

__global__ void wcvt_kernel(const float* __restrict__ w, unsigned short* __restrict__ wt) {
  int i = blockIdx.x * 256 + threadIdx.x;     // over 9*256*128
  if (i >= 9 * COUT * CIN) return;
  int o = i / (COUT * CIN);
  int r = i % (COUT * CIN);
  int co = r / CIN, c = r % CIN;
  int dh = o / 3, dw = o % 3;
  wt[i] = f2bf(w[((co * CIN + c) * 3 + dh) * 3 + dw]);
}

// block = (n, s'-block of 64 source positions). Reads coalesced, writes 256B c-lines.
__global__ __launch_bounds__(256) void pad_perm_kernel(const float* __restrict__ x,
                                                       const int* __restrict__ inv,
                                                       unsigned short* __restrict__ xp) {
  __shared__ unsigned short T[64 * 128];   // row j: 256B, XOR-swizzled in 16B chunks
  __shared__ int dest_off[64];
  int b = blockIdx.x;            // 0..1567
  int n = b / 49;
  int s0 = (b % 49) * 64;
  int t = threadIdx.x;

  if (t < 64) {
    int s = inv[s0 + t];         // dest position for source s0+t
    int h = s / HH, w = s % HH;
    dest_off[t] = ((n * HP + h + 1) * HP + (w + 1)) * CIN;
  }
  const float* xplane = x + (size_t)n * CIN * HW;
  #pragma unroll
  for (int i = 0; i < 32; ++i) {
    int idx = i * 256 + t;
    int c = idx >> 6, j = idx & 63;
    float v = xplane[c * HW + s0 + j];
    int byte = j * 256 + ((2 * c) ^ ((j & 7) << 4));
    *(unsigned short*)((char*)T + byte) = f2bf(v);
  }
  __syncthreads();
  #pragma unroll
  for (int i = 0; i < 4; ++i) {
    int u = i * 256 + t;
    int j = u >> 4, chunk = u & 15;
    int byte = j * 256 + ((chunk * 16) ^ ((j & 7) << 4));
    bf16x8 v = *(const bf16x8*)((const char*)T + byte);
    *(bf16x8*)(xp + dest_off[j] + chunk * 8) = v;
  }
}

// Implicit GEMM conv: tile 128 Cout x 128 px, BK=32, 9 offsets x 4 c-blocks.
__global__ __launch_bounds__(256) void conv_kernel(const unsigned short* __restrict__ xp,
                                                   const unsigned short* __restrict__ wt,
                                                   float* __restrict__ out) {
  __shared__ __align__(16) unsigned short A_lds[128 * 32];
  __shared__ __align__(16) unsigned short B_lds[128 * 32];
  int b = blockIdx.x;           // 0..1567
  int coT = b & 1;
  int pT = b >> 1;              // 0..783
  int t = threadIdx.x;
  int lane = t & 63;
  int wid = t >> 6;
  int wm = wid >> 1, wn = wid & 1;

  int p0 = pT * 128;
  long bsrc[2];
  #pragma unroll
  for (int i = 0; i < 2; ++i) {
    int p = i * 64 + (t >> 2);
    int flat = p0 + p;
    int n = flat / HW, s = flat % HW;
    int h = s / HH, w = s % HH;
    bsrc[i] = (long)((n * HP + h) * HP + w) * CIN + (t & 3) * 8;
  }
  int ac0 = (t & 3) * 8;
  int aco0 = (t >> 2);          // issue 0 row; issue 1 = +64

  f32x4 acc[4][4];
  #pragma unroll
  for (int m = 0; m < 4; ++m)
    #pragma unroll
    for (int q = 0; q < 4; ++q) acc[m][q] = (f32x4)0.f;

  for (int kk = 0; kk < 36; ++kk) {
    int o = kk >> 2;            // 0..8
    int cb = kk & 3;            // 0..3
    int dh = o / 3, dw = o % 3;

    // stage A (weights): 128x32 bf16
    #pragma unroll
    for (int i = 0; i < 2; ++i) {
      const unsigned short* src = wt + ((o * COUT + coT * 128 + aco0 + i * 64) * CIN + cb * 32 + ac0);
      gload_lds16(src, &A_lds[(i * 256 + t) * 8]);
    }
    // stage B (pixels): 128x32 bf16
    int boff = (dh * HP + dw) * CIN + cb * 32;
    #pragma unroll
    for (int i = 0; i < 2; ++i) {
      const unsigned short* src = xp + bsrc[i] + boff;
      gload_lds16(src, &B_lds[(i * 256 + t) * 8]);
    }
    __syncthreads();   // drains vmcnt -> LDS ready

    bf16x8 af[4], bfr[4];
    int krow = (lane >> 4) * 8;
    #pragma unroll
    for (int m = 0; m < 4; ++m)
      af[m] = *(const bf16x8*)&A_lds[(wm * 64 + m * 16 + (lane & 15)) * 32 + krow];
    #pragma unroll
    for (int q = 0; q < 4; ++q)
      bfr[q] = *(const bf16x8*)&B_lds[(wn * 64 + q * 16 + (lane & 15)) * 32 + krow];
    #pragma unroll
    for (int m = 0; m < 4; ++m)
      #pragma unroll
      for (int q = 0; q < 4; ++q)
        acc[m][q] = __builtin_amdgcn_mfma_f32_16x16x32_bf16(af[m], bfr[q], acc[m][q], 0, 0, 0);
    __syncthreads();
  }

  // epilogue: D row = co, col = px; C/D map col=lane&15, row=(lane>>4)*4+j
  #pragma unroll
  for (int q = 0; q < 4; ++q) {
    int px = p0 + wn * 64 + q * 16 + (lane & 15);
    int nimg = px / HW, s = px % HW;
    float* obase = out + (size_t)nimg * COUT * HW + s;
    #pragma unroll
    for (int m = 0; m < 4; ++m) {
      int co = coT * 128 + wm * 64 + m * 16 + ((lane >> 4) * 4);
      #pragma unroll
      for (int j = 0; j < 4; ++j)
        obase[(size_t)(co + j) * HW] = acc[m][q][j];
    }
  }
}

__global__ __launch_bounds__(256) void stats_kernel(const float* __restrict__ y,
                                                    float* __restrict__ stats) {
  int b = blockIdx.x;          // n*256+co
  int co = b & 255;
  const float* p = y + (size_t)b * HW;
  float s1 = 0.f, s2 = 0.f;
  for (int i = threadIdx.x; i < HW; i += 256) {
    float v = p[i];
    s1 += v; s2 += v * v;
  }
  #pragma unroll
  for (int off = 32; off; off >>= 1) {
    s1 += __shfl_down(s1, off);
    s2 += __shfl_down(s2, off);
  }
  __shared__ float r1[4], r2[4];
  int wid = threadIdx.x >> 6;
  if ((threadIdx.x & 63) == 0) { r1[wid] = s1; r2[wid] = s2; }
  __syncthreads();
  if (threadIdx.x == 0) {
    s1 = r1[0] + r1[1] + r1[2] + r1[3];
    s2 = r2[0] + r2[1] + r2[2] + r2[3];
    atomicAdd(&stats[co], s1);
    atomicAdd(&stats[256 + co], s2);
  }
}

__global__ void bnparam_kernel(const float* __restrict__ stats,
                               const float* __restrict__ gamma,
                               const float* __restrict__ beta,
                               float* __restrict__ ss) {
  int c = threadIdx.x;  // 256
  float cnt = (float)(N_IMG * HW);
  float mean = stats[c] / cnt;
  float var = stats[256 + c] / cnt - mean * mean;
  float sc = gamma[c] * rsqrtf(var + 1e-5f);
  ss[c] = sc;
  ss[256 + c] = beta[c] - mean * sc;
}

__global__ __launch_bounds__(256) void bnrelu_kernel(float* __restrict__ y,
                                                     const float* __restrict__ ss) {
  int idx = blockIdx.x * 256 + threadIdx.x;   // float4 index
  if (idx >= (N_IMG * COUT * HW) / 4) return;
  int plane = idx / (HW / 4);
  int co = plane & 255;
  float sc = ss[co], sh = ss[256 + co];
  float4 v = ((float4*)y)[idx];
  v.x = fmaxf(v.x * sc + sh, 0.f);
  v.y = fmaxf(v.y * sc + sh, 0.f);
  v.z = fmaxf(v.z * sc + sh, 0.f);
  v.w = fmaxf(v.w * sc + sh, 0.f);
  ((float4*)y)[idx] = v;
}

extern "C" void kernel_launch(void* const* d_in, const int* in_sizes, int n_in,
                              void* d_out, int out_size, void* d_ws, size_t ws_size,
                              hipStream_t stream) {
  const float* x     = (const float*)d_in[0];
  const float* w     = (const float*)d_in[1];
  const float* gamma = (const float*)d_in[2];
  const float* beta  = (const float*)d_in[3];
  const int*   perm  = (const int*)d_in[4];
  float* out = (float*)d_out;
  char* ws = (char*)d_ws;

  unsigned short* xp = (unsigned short*)ws;
  unsigned short* wt = (unsigned short*)(ws + XP_BYTES);
  int* inv           = (int*)(ws + XP_BYTES + WT_BYTES);
  float* stats       = (float*)(ws + XP_BYTES + WT_BYTES + INV_BYTES);
  float* ss          = (float*)(ws + XP_BYTES + WT_BYTES + INV_BYTES + STATS_BYTES);

  hipMemsetAsync(xp, 0, XP_BYTES, stream);
  hipMemsetAsync(stats, 0, STATS_BYTES, stream);

  invperm_kernel<<<(HW + 255) / 256, 256, 0, stream>>>(perm, inv);
  wcvt_kernel<<<(9 * COUT * CIN + 255) / 256, 256, 0, stream>>>(w, wt);
  pad_perm_kernel<<<N_IMG * 49, 256, 0, stream>>>(x, inv, xp);
  conv_kernel<<<1568, 256, 0, stream>>>(xp, wt, out);
  stats_kernel<<<N_IMG * COUT, 256, 0, stream>>>(out, stats);
  bnparam_kernel<<<1, 256, 0, stream>>>(stats, gamma, beta, ss);
  bnrelu_kernel<<<(N_IMG * COUT * HW / 4 + 255) / 256, 256, 0, stream>>>(out, ss);
}